// Round 13
// baseline (466.819 us; speedup 1.0000x reference)
//
#include <hip/hip_runtime.h>
#include <hip/hip_bf16.h>

using bf16 = __hip_bfloat16;
typedef __attribute__((ext_vector_type(8))) short bf16x8;
typedef __attribute__((ext_vector_type(4))) float f32x4;

// Shapes fixed: B=2, S=2048, D=1024, H=16, hd=64, F=2048.
// 8 slots of 4MB (M2 = 2M bf16 elems): r0..r3 (ws), pb0 a/b, pb1 a/b (out).
// Schedule identical to r12 (audited there). r13 change: attn QBLK=32 with
// 128-thread blocks -> grid 2048 = ~7 blocks/CU co-resident (was 4,
// grid-limited); per-wave work per K-tile unchanged.

__device__ inline float toF(float x) { return x; }
__device__ inline float toF(bf16 x) { return __bfloat162float(x); }

__device__ __forceinline__ void unpack8(uint4 u, float* f) {
    f[0] = __uint_as_float(u.x << 16); f[1] = __uint_as_float(u.x & 0xffff0000u);
    f[2] = __uint_as_float(u.y << 16); f[3] = __uint_as_float(u.y & 0xffff0000u);
    f[4] = __uint_as_float(u.z << 16); f[5] = __uint_as_float(u.z & 0xffff0000u);
    f[6] = __uint_as_float(u.w << 16); f[7] = __uint_as_float(u.w & 0xffff0000u);
}

__device__ __forceinline__ uint4 packbf8(const float* f) {
    union { unsigned short u[8]; uint4 v; } r;
#pragma unroll
    for (int i = 0; i < 8; i++) {
        bf16 b = __float2bfloat16(f[i]);
        r.u[i] = *(unsigned short*)&b;
    }
    return r.v;
}

__device__ __forceinline__ unsigned pack2(float lo, float hi) {
    bf16 a = __float2bfloat16(lo), b = __float2bfloat16(hi);
    return ((unsigned)*(unsigned short*)&b << 16) | (unsigned)*(unsigned short*)&a;
}

__device__ __forceinline__ void gl_lds16(const void* g, void* l) {
    __builtin_amdgcn_global_load_lds(
        (__attribute__((address_space(1))) void*)g,
        (__attribute__((address_space(3))) void*)l, 16, 0, 0);
}

// ---------------------------------------------------------------------------
// LN body: one block per row, D=1024, 256 threads.
// ---------------------------------------------------------------------------
template <typename Tx>
__device__ __forceinline__ void ln_body(
    const Tx* __restrict__ x, const float* __restrict__ g,
    const float* __restrict__ b, bf16* __restrict__ out, int row,
    float* s1, float* s2)
{
    const int D = 1024;
    int tid = threadIdx.x;
    const Tx* xr = x + (size_t)row * D;

    float vals[4];
    float sum = 0.f, sumsq = 0.f;
#pragma unroll
    for (int i = 0; i < 4; i++) {
        float v = toF(xr[tid + i * 256]);
        vals[i] = v; sum += v; sumsq += v * v;
    }
#pragma unroll
    for (int off = 32; off > 0; off >>= 1) {
        sum += __shfl_xor(sum, off);
        sumsq += __shfl_xor(sumsq, off);
    }
    int wave = tid >> 6, lane = tid & 63;
    if (lane == 0) { s1[wave] = sum; s2[wave] = sumsq; }
    __syncthreads();
    sum = s1[0] + s1[1] + s1[2] + s1[3];
    sumsq = s2[0] + s2[1] + s2[2] + s2[3];

    float mu = sum * (1.f / D);
    float var = sumsq * (1.f / D) - mu * mu;
    float rstd = rsqrtf(var + 1e-5f);

    bf16* orow = out + (size_t)row * D;
#pragma unroll
    for (int i = 0; i < 4; i++) {
        int c = tid + i * 256;
        orow[c] = __float2bfloat16((vals[i] - mu) * rstd * g[c] + b[c]);
    }
}

// ---------------------------------------------------------------------------
// prep1F: blocks [0,4096): LN1 rows, both batches (b = bx>>11)
//         blocks [4096,7168): WqT/WkT/WvT transpose (48 z-slices)
// ---------------------------------------------------------------------------
__global__ __launch_bounds__(256) void prep1_kernel(
    const float* __restrict__ x, const float* __restrict__ g,
    const float* __restrict__ b, bf16* __restrict__ h0, bf16* __restrict__ h1,
    const float* __restrict__ Wq, const float* __restrict__ Wk,
    const float* __restrict__ Wv, bf16* __restrict__ wt)
{
    __shared__ float t[32][33];
    __shared__ float s1[4], s2[4];
    int bx = blockIdx.x;
    if (bx < 4096) {
        int bb = bx >> 11, row = bx & 2047;
        ln_body<float>(x + ((size_t)bb << 21), g, b, bb ? h1 : h0, row, s1, s2);
        return;
    }
    int zz = bx - 4096;
    int z = zz >> 6, rem = zz & 63;
    int yy = rem >> 1, xx = rem & 1;
    const float* s = (z < 16) ? Wq : (z < 32) ? Wk : Wv;
    const float* ip = s + (size_t)(z & 15) * 65536;
    bf16* op = wt + ((size_t)z << 16);
    int c0 = xx * 32, r0 = yy * 32;
    int tx = threadIdx.x & 31, ty = threadIdx.x >> 5;
#pragma unroll
    for (int i = 0; i < 4; i++)
        t[ty + 8 * i][tx] = ip[(size_t)(r0 + ty + 8 * i) * 64 + c0 + tx];
    __syncthreads();
#pragma unroll
    for (int i = 0; i < 4; i++)
        op[(size_t)(c0 + ty + 8 * i) * 1024 + r0 + tx] = __float2bfloat16(t[tx][ty + 8 * i]);
}

// ---------------------------------------------------------------------------
// prep2: blocks [0,2048): LN2 row; [2048,6144): W1T/W2T; [6144,8192): W3T
// ---------------------------------------------------------------------------
__global__ __launch_bounds__(256) void prep2_kernel(
    const bf16* __restrict__ x2, const float* __restrict__ g,
    const float* __restrict__ b, bf16* __restrict__ h2,
    const float* __restrict__ W1, const float* __restrict__ W2,
    bf16* __restrict__ wt, const float* __restrict__ W3,
    bf16* __restrict__ w3t)
{
    __shared__ float t[32][33];
    __shared__ float s1[4], s2[4];
    int bx = blockIdx.x;
    if (bx < 2048) {
        ln_body<bf16>(x2, g, b, h2, bx, s1, s2);
        return;
    }
    int tx = threadIdx.x & 31, ty = threadIdx.x >> 5;
    int zz = bx - 2048;
    if (zz < 4096) {
        int xx = zz & 63, yy = (zz >> 6) & 31, z = zz >> 11;
        const float* ip = z ? W2 : W1;
        bf16* op = wt + ((size_t)z << 21);
        int c0 = xx * 32, r0 = yy * 32;
#pragma unroll
        for (int i = 0; i < 4; i++)
            t[ty + 8 * i][tx] = ip[(size_t)(r0 + ty + 8 * i) * 2048 + c0 + tx];
        __syncthreads();
#pragma unroll
        for (int i = 0; i < 4; i++)
            op[(size_t)(c0 + ty + 8 * i) * 1024 + r0 + tx] = __float2bfloat16(t[tx][ty + 8 * i]);
        return;
    }
    int idx = zz - 4096;
    int xx = idx & 31, yy = idx >> 5;
    int c0 = xx * 32, r0 = yy * 32;
#pragma unroll
    for (int i = 0; i < 4; i++)
        t[ty + 8 * i][tx] = W3[(size_t)(r0 + ty + 8 * i) * 1024 + c0 + tx];
    __syncthreads();
#pragma unroll
    for (int i = 0; i < 4; i++)
        w3t[(size_t)(c0 + ty + 8 * i) * 2048 + r0 + tx] = __float2bfloat16(t[tx][ty + 8 * i]);
}

// ---------------------------------------------------------------------------
// Generic transpose+convert (W3 for batch 1): fp32 [R][C] -> bf16 [C][R].
// ---------------------------------------------------------------------------
__global__ __launch_bounds__(256) void tconv_kernel(
    const float* __restrict__ in, bf16* __restrict__ out, int R, int C)
{
    __shared__ float t[32][33];
    int c0 = blockIdx.x * 32, r0 = blockIdx.y * 32;
    int tx = threadIdx.x & 31, ty = threadIdx.x >> 5;
#pragma unroll
    for (int i = 0; i < 4; i++)
        t[ty + 8 * i][tx] = in[(size_t)(r0 + ty + 8 * i) * C + c0 + tx];
    __syncthreads();
#pragma unroll
    for (int i = 0; i < 4; i++)
        out[(size_t)(c0 + ty + 8 * i) * R + r0 + tx] = __float2bfloat16(t[tx][ty + 8 * i]);
}

// Wo transpose: 16 64-col slices of [1024][1024] -> [64][1024] each.
__global__ __launch_bounds__(256) void tconv_wo_kernel(
    const float* __restrict__ Wo, bf16* __restrict__ out)
{
    __shared__ float t[32][33];
    int z = blockIdx.z;
    const float* ip = Wo + (size_t)z * 64;
    bf16* op = out + ((size_t)z << 16);
    int c0 = blockIdx.x * 32, r0 = blockIdx.y * 32;
    int tx = threadIdx.x & 31, ty = threadIdx.x >> 5;
#pragma unroll
    for (int i = 0; i < 4; i++)
        t[ty + 8 * i][tx] = ip[(size_t)(r0 + ty + 8 * i) * 1024 + c0 + tx];
    __syncthreads();
#pragma unroll
    for (int i = 0; i < 4; i++)
        op[(size_t)(c0 + ty + 8 * i) * 1024 + r0 + tx] = __float2bfloat16(t[tx][ty + 8 * i]);
}

// ---------------------------------------------------------------------------
// MFMA GEMM: C[M,N] = A[M,K](bf16) @ B (BT[N,K] bf16), fp32 accum.
// 64x64 tile, BK=64 double-buffer, 4 waves (2x2), wave tile 32x32.
// MODE 1 (QK): z=0/1 = q/k: BT=BT0+z*1M; C = z ? p6 : Cv. RoPE scatter.
// MODE 6 (V^T, both batches): z=0: A,Cv; z=1: p5,p6. vt[h][d][s] direct.
// MODE 2 (F): z=batch: A=A/p5, res=resv fp32 +z*2M, C=Cv/p6; bf16=acc+res.
// MODE 4: C f32 = acc + resBf16
// ---------------------------------------------------------------------------
template <int MODE>
__global__ __launch_bounds__(256) void mfma_gemm(
    const bf16* __restrict__ A, const bf16* __restrict__ BT0,
    void* __restrict__ Cv, const void* __restrict__ resv,
    const void* __restrict__ p5, void* __restrict__ p6,
    int M, int N, int K)
{
    __shared__ bf16 smem[2][2][64 * 64];               // 32KB
    int tid = threadIdx.x, lane = tid & 63, w = tid >> 6;
    int wm = w >> 1, wn = w & 1;
    int m0 = blockIdx.y * 64, n0 = blockIdx.x * 64;

    const bf16* Ap = A;
    const bf16* BT = BT0;
    bf16* Cq = nullptr;
    const float* resF = (const float*)resv;
    void* Cdst = Cv;
    if (MODE == 1) {
        int z = blockIdx.z;
        BT = BT0 + ((size_t)z << 20);
        Cq = (bf16*)(z ? p6 : Cv);
    }
    if (MODE == 6) {
        int z = blockIdx.z;
        if (z) { Ap = (const bf16*)p5; Cq = (bf16*)p6; }
        else Cq = (bf16*)Cv;
    }
    if (MODE == 2) {
        int z = blockIdx.z;
        if (z) { Ap = (const bf16*)p5; Cdst = p6; }
        resF = (const float*)resv + ((size_t)z << 21);
    }

    int lrow = lane >> 3;
    int lcb  = (lane & 7) ^ lrow;
    const bf16* Ag  = Ap + (size_t)(m0 + w * 8 + lrow) * K + lcb * 8;
    const bf16* Bg0 = BT + (size_t)(n0 + w * 8 + lrow) * K + lcb * 8;
    unsigned sbase = (unsigned)__builtin_amdgcn_readfirstlane(w * 8 * 128);
    char* smc = (char*)smem;

    f32x4 acc[2][2];
#pragma unroll
    for (int i = 0; i < 2; i++)
#pragma unroll
        for (int j = 0; j < 2; j++) acc[i][j] = (f32x4){0.f, 0.f, 0.f, 0.f};

    int cidx = lane & 15, quad = lane >> 4;

    auto STAGE = [&](int buf, int k0) {
        char* p = smc + (size_t)buf * 16384 + sbase;
        gl_lds16(Ag + k0,                   p);
        gl_lds16(Ag + (size_t)32 * K + k0,  p + 4096);
        gl_lds16(Bg0 + k0,                  p + 8192);
        gl_lds16(Bg0 + (size_t)32 * K + k0, p + 12288);
    };

    STAGE(0, 0);
    __syncthreads();
    int cur = 0;
    for (int k0 = 0; k0 < K; k0 += 64) {
        if (k0 + 64 < K) STAGE(cur ^ 1, k0 + 64);
        const bf16* Ab = (const bf16*)(smc + (size_t)cur * 16384);
        const bf16* Bb = Ab + 4096;
#pragma unroll
        for (int kk = 0; kk < 2; kk++) {
            int pb = (kk * 4 + quad) ^ (cidx & 7);
            bf16x8 af[2], bfr[2];
#pragma unroll
            for (int i = 0; i < 2; i++)
                af[i] = *(const bf16x8*)&Ab[(wm * 32 + i * 16 + cidx) * 64 + pb * 8];
#pragma unroll
            for (int j = 0; j < 2; j++)
                bfr[j] = *(const bf16x8*)&Bb[(wn * 32 + j * 16 + cidx) * 64 + pb * 8];
            __builtin_amdgcn_s_setprio(1);
#pragma unroll
            for (int i = 0; i < 2; i++)
#pragma unroll
                for (int j = 0; j < 2; j++)
                    acc[i][j] = __builtin_amdgcn_mfma_f32_16x16x32_bf16(af[i], bfr[j], acc[i][j], 0, 0, 0);
            __builtin_amdgcn_s_setprio(0);
        }
        __syncthreads();
        cur ^= 1;
    }

    int rbase = quad * 4;
#pragma unroll
    for (int i = 0; i < 2; i++) {
#pragma unroll
        for (int j = 0; j < 2; j++) {
            int row0 = m0 + wm * 32 + i * 16 + rbase;
            int col = n0 + wn * 32 + j * 16 + cidx;
            if (MODE == 6) {
                int h_ = col >> 6, d = col & 63;
                uint2 t;
                t.x = pack2(acc[i][j][0], acc[i][j][1]);
                t.y = pack2(acc[i][j][2], acc[i][j][3]);
                *(uint2*)&Cq[(size_t)h_ * 131072 + (size_t)d * 2048 + row0] = t;
                continue;
            }
#pragma unroll
            for (int r = 0; r < 4; r++) {
                int row = row0 + r;
                float v = acc[i][j][r];
                size_t idx = (size_t)row * N + col;
                if (MODE == 1) {
                    int h_ = col >> 6, kk = col & 63;
                    float other = __shfl_xor(v, 1);
                    float p = (float)(kk >> 1);
                    float theta = __expf(p * -0.5756462732485114f); // ln(1e4)/16
                    float ang = (float)row * theta;
                    float c, sn; __sincosf(ang, &sn, &c);
                    float outv = (kk & 1) ? (v * c + other * sn) : (v * c - other * sn);
                    Cq[((size_t)h_ * 2048 + row) * 64 + kk] = __float2bfloat16(outv);
                } else if (MODE == 2) {
                    v += resF[idx];
                    ((bf16*)Cdst)[idx] = __float2bfloat16(v);
                } else {
                    v += __bfloat162float(((const bf16*)resv)[idx]);
                    ((float*)Cv)[idx] = v;
                }
            }
        }
    }
}

// ---------------------------------------------------------------------------
// SwiGLU GEMM: C = silu(A@W1) * (A@W2). 128x64 tile, BK=64 dbuf, 4 waves,
// wave tile 64x32 (af-reuse 4). Grid 512 = 2/CU exact. (r12-proven.)
// ---------------------------------------------------------------------------
__global__ __launch_bounds__(256) void swiglu_gemm(
    const bf16* __restrict__ A, const bf16* __restrict__ B1T,
    const bf16* __restrict__ B2T, bf16* __restrict__ C)
{
    const int K = 1024, N = 2048;
    __shared__ bf16 smem[2][16384];
    int tid = threadIdx.x, lane = tid & 63, w = tid >> 6;
    int wm = w >> 1, wn = w & 1;
    int m0 = blockIdx.y * 128, n0 = blockIdx.x * 64;

    int lrow = lane >> 3;
    int lcb  = (lane & 7) ^ lrow;
    const bf16* Ag  = A   + (size_t)(m0 + w * 8 + lrow) * K + lcb * 8;
    const bf16* B1g = B1T + (size_t)(n0 + w * 8 + lrow) * K + lcb * 8;
    const bf16* B2g = B2T + (size_t)(n0 + w * 8 + lrow) * K + lcb * 8;
    unsigned sbase = (unsigned)__builtin_amdgcn_readfirstlane(w * 8 * 128);
    char* smc = (char*)smem;

    f32x4 acc[4][2], acc2[4][2];
#pragma unroll
    for (int i = 0; i < 4; i++)
#pragma unroll
        for (int j = 0; j < 2; j++) {
            acc[i][j] = (f32x4){0.f, 0.f, 0.f, 0.f};
            acc2[i][j] = (f32x4){0.f, 0.f, 0.f, 0.f};
        }

    int cidx = lane & 15, quad = lane >> 4;

    auto STAGE = [&](int buf, int k0) {
        char* p = smc + (size_t)buf * 32768 + sbase;
#pragma unroll
        for (int n = 0; n < 4; n++)
            gl_lds16(Ag + (size_t)(n * 32) * K + k0, p + n * 4096);
#pragma unroll
        for (int n = 0; n < 2; n++) {
            gl_lds16(B1g + (size_t)(n * 32) * K + k0, p + 16384 + n * 4096);
            gl_lds16(B2g + (size_t)(n * 32) * K + k0, p + 24576 + n * 4096);
        }
    };

    STAGE(0, 0);
    __syncthreads();
    int cur = 0;
    for (int k0 = 0; k0 < K; k0 += 64) {
        if (k0 + 64 < K) STAGE(cur ^ 1, k0 + 64);
        const bf16* Ab = (const bf16*)(smc + (size_t)cur * 32768);
        const bf16* Bb = Ab + 8192;
        const bf16* B2b = Ab + 12288;
#pragma unroll
        for (int kk = 0; kk < 2; kk++) {
            int pb = (kk * 4 + quad) ^ (cidx & 7);
            bf16x8 af[4], bfr[2], b2f[2];
#pragma unroll
            for (int i = 0; i < 4; i++)
                af[i] = *(const bf16x8*)&Ab[(wm * 64 + i * 16 + cidx) * 64 + pb * 8];
#pragma unroll
            for (int j = 0; j < 2; j++) {
                bfr[j] = *(const bf16x8*)&Bb[(wn * 32 + j * 16 + cidx) * 64 + pb * 8];
                b2f[j] = *(const bf16x8*)&B2b[(wn * 32 + j * 16 + cidx) * 64 + pb * 8];
            }
            __builtin_amdgcn_s_setprio(1);
#pragma unroll
            for (int i = 0; i < 4; i++)
#pragma unroll
                for (int j = 0; j < 2; j++) {
                    acc[i][j] = __builtin_amdgcn_mfma_f32_16x16x32_bf16(af[i], bfr[j], acc[i][j], 0, 0, 0);
                    acc2[i][j] = __builtin_amdgcn_mfma_f32_16x16x32_bf16(af[i], b2f[j], acc2[i][j], 0, 0, 0);
                }
            __builtin_amdgcn_s_setprio(0);
        }
        __syncthreads();
        cur ^= 1;
    }

    int rbase = quad * 4;
#pragma unroll
    for (int i = 0; i < 4; i++) {
#pragma unroll
        for (int j = 0; j < 2; j++) {
#pragma unroll
            for (int r = 0; r < 4; r++) {
                int row = m0 + wm * 64 + i * 16 + rbase + r;
                int col = n0 + wn * 32 + j * 16 + cidx;
                float u = acc[i][j][r];
                float g2 = acc2[i][j][r];
                float sg = 1.f / (1.f + __expf(-u));
                C[(size_t)row * N + col] = __float2bfloat16(u * sg * g2);
            }
        }
    }
}

// ---------------------------------------------------------------------------
// MFMA causal flash attention, BOTH batches (z = batch). hd=64.
// r13: QBLK=32, 128-thread blocks (2 waves), KVBLK=64. Grid (64,16,2) =
// 2048 blocks -> ~7 co-resident blocks/CU (was 4, grid-limited at 26% occ).
// Per-wave work per K-tile unchanged from the proven r9 kernel: wave w owns
// 16 q-rows (w*16..+16), 8 QK + 8 PV MFMA, reg-prefetch + 2 barriers,
// XOR-swizzled [64][64] K/V LDS, deferred-l + defer-max log2 softmax,
// P^T wave-private strip. Each thread stages rows {srow, srow+32} of K,V
// ((srow+32)&7 == srow&7, swizzle formulas unchanged).
// LDS: Ks 8K + Vs 8K + QP 4.6K = 20.6KB.
// ---------------------------------------------------------------------------
__global__ __launch_bounds__(128) void attn_kernel(
    const bf16* __restrict__ q0, const bf16* __restrict__ k0,
    const bf16* __restrict__ vt0, bf16* __restrict__ o0,
    const bf16* __restrict__ q1, const bf16* __restrict__ k1,
    const bf16* __restrict__ vt1, bf16* __restrict__ o1)
{
    const int S = 2048;
    __shared__ bf16 Ks[64 * 64];
    __shared__ bf16 Vs[64 * 64];
    __shared__ __align__(16) char QPbuf[32 * 72 * 2];   // 4608B: Q stage / P strips

    int zb = blockIdx.z;
    const bf16* q = zb ? q1 : q0;
    const bf16* k = zb ? k1 : k0;
    const bf16* vt = zb ? vt1 : vt0;
    bf16* o = zb ? o1 : o0;

    int h = blockIdx.y;
    int qt = (h & 8) ? (int)blockIdx.x : 63 - (int)blockIdx.x;
    int tid = threadIdx.x, lane = tid & 63, w = tid >> 6;   // w in {0,1}
    int quad = lane >> 4, cidx = lane & 15;
    int m0 = qt * 32;

    const bf16* qb = q + ((size_t)h * S + m0) * 64;
    const bf16* kb = k + (size_t)h * S * 64;
    const bf16* vtb = vt + (size_t)h * 64 * S;

    int srow = tid >> 2;          // 0..31 (staging row; also +32 for K/V)
    int sg = (tid & 3) * 16;

    // ---- stage Q (32 rows) * (0.125*log2e); wave w stages rows w*16..+15
    bf16 (*Qs)[72] = (bf16 (*)[72])QPbuf;
    {
        const uint4* src = (const uint4*)(qb + (size_t)srow * 64 + sg);
        uint4 u0 = src[0], u1 = src[1];
        float f[16]; unpack8(u0, f); unpack8(u1, f + 8);
#pragma unroll
        for (int i = 0; i < 16; i++) f[i] *= 0.125f * 1.44269504f;
        *(uint4*)&Qs[srow][sg] = packbf8(f);
        *(uint4*)&Qs[srow][sg + 8] = packbf8(f + 8);
    }
    // same-wave LDS write->read (wave-private rows); no barrier needed
    bf16x8 bQ0 = *(const bf16x8*)&Qs[w * 16 + cidx][quad * 8];
    bf16x8 bQ1 = *(const bf16x8*)&Qs[w * 16 + cidx][32 + quad * 8];

    unsigned* Pst = (unsigned*)QPbuf + w * 576;

    int cb0 = (tid & 3) * 2;
    int sw0 = ((cb0)     ^ (srow & 7)) * 8;
    int sw1 = ((cb0 + 1) ^ (srow & 7)) * 8;
    int pb0 = ((quad)     ^ (cidx & 7)) * 8;
    int pb1 = ((4 + quad) ^ (cidx & 7)) * 8;

    float m_i = -INFINITY, l_i = 0.f;
    f32x4 Oc[4];
#pragma unroll
    for (int i = 0; i < 4; i++) Oc[i] = (f32x4){0.f, 0.f, 0.f, 0.f};

    int nt = qt / 2 + 1;          // 64-row KV tiles covering [0, m0+32)

    // prefetch tile kt=0: rows srow and srow+32 of K and V^T
    uint4 ka[4], va[4];
    {
        const uint4* k0p = (const uint4*)(kb + (size_t)srow * 64 + sg);
        const uint4* k1p = (const uint4*)(kb + (size_t)(srow + 32) * 64 + sg);
        ka[0] = k0p[0]; ka[1] = k0p[1]; ka[2] = k1p[0]; ka[3] = k1p[1];
        const uint4* v0p = (const uint4*)(vtb + (size_t)srow * S + sg);
        const uint4* v1p = (const uint4*)(vtb + (size_t)(srow + 32) * S + sg);
        va[0] = v0p[0]; va[1] = v0p[1]; va[2] = v1p[0]; va[3] = v1p[1];
    }

    for (int kt = 0; kt < nt; kt++) {
        __syncthreads();
        *(uint4*)&Ks[srow * 64 + sw0] = ka[0];
        *(uint4*)&Ks[srow * 64 + sw1] = ka[1];
        *(uint4*)&Ks[(srow + 32) * 64 + sw0] = ka[2];
        *(uint4*)&Ks[(srow + 32) * 64 + sw1] = ka[3];
        *(uint4*)&Vs[srow * 64 + sw0] = va[0];
        *(uint4*)&Vs[srow * 64 + sw1] = va[1];
        *(uint4*)&Vs[(srow + 32) * 64 + sw0] = va[2];
        *(uint4*)&Vs[(srow + 32) * 64 + sw1] = va[3];
        __syncthreads();
        if (kt + 1 < nt) {
            const bf16* kn = kb + (size_t)((kt + 1) * 64) * 64;
            const uint4* k0p = (const uint4*)(kn + (size_t)srow * 64 + sg);
            const uint4* k1p = (const uint4*)(kn + (size_t)(srow + 32) * 64 + sg);
            ka[0] = k0p[0]; ka[1] = k0p[1]; ka[2] = k1p[0]; ka[3] = k1p[1];
            const bf16* vn = vtb + (kt + 1) * 64;
            const uint4* v0p = (const uint4*)(vn + (size_t)srow * S + sg);
            const uint4* v1p = (const uint4*)(vn + (size_t)(srow + 32) * S + sg);
            va[0] = v0p[0]; va[1] = v0p[1]; va[2] = v1p[0]; va[3] = v1p[1];
        }

        // S^T: sc[i] = S^T[kpos=kt*64+i*16+quad*4+r][q=w*16+cidx] (log2 dom)
        f32x4 sc[4];
#pragma unroll
        for (int i = 0; i < 4; i++) {
            bf16x8 aK0 = *(const bf16x8*)&Ks[(i * 16 + cidx) * 64 + pb0];
            bf16x8 aK1 = *(const bf16x8*)&Ks[(i * 16 + cidx) * 64 + pb1];
            f32x4 z = (f32x4){0.f, 0.f, 0.f, 0.f};
            __builtin_amdgcn_s_setprio(1);
            z = __builtin_amdgcn_mfma_f32_16x16x32_bf16(aK0, bQ0, z, 0, 0, 0);
            z = __builtin_amdgcn_mfma_f32_16x16x32_bf16(aK1, bQ1, z, 0, 0, 0);
            __builtin_amdgcn_s_setprio(0);
            sc[i] = z;
        }

        if (kt == nt - 1) {       // causal mask: kpos > q
            int qpos = m0 + w * 16 + cidx;
#pragma unroll
            for (int i = 0; i < 4; i++)
#pragma unroll
                for (int r = 0; r < 4; r++)
                    if (kt * 64 + i * 16 + quad * 4 + r > qpos) sc[i][r] = -INFINITY;
        }

        float l0 = fmaxf(fmaxf(sc[0][0], sc[0][1]), fmaxf(sc[0][2], sc[0][3]));
        float l1 = fmaxf(fmaxf(sc[1][0], sc[1][1]), fmaxf(sc[1][2], sc[1][3]));
        float l2 = fmaxf(fmaxf(sc[2][0], sc[2][1]), fmaxf(sc[2][2], sc[2][3]));
        float l3 = fmaxf(fmaxf(sc[3][0], sc[3][1]), fmaxf(sc[3][2], sc[3][3]));
        float lmax = fmaxf(fmaxf(l0, l1), fmaxf(l2, l3));

        if (!__all(lmax <= m_i + 8.f)) {
            float pmax = fmaxf(lmax, __shfl_xor(lmax, 16));
            pmax = fmaxf(pmax, __shfl_xor(pmax, 32));
            float mnew = fmaxf(m_i, pmax);
            float alpha = __builtin_amdgcn_exp2f(m_i - mnew);
            l_i *= alpha;
#pragma unroll
            for (int i = 0; i < 4; i++) {
                Oc[i][0] *= alpha; Oc[i][1] *= alpha;
                Oc[i][2] *= alpha; Oc[i][3] *= alpha;
            }
            m_i = mnew;
        }

        float rs = 0.f;
#pragma unroll
        for (int i = 0; i < 4; i++)
#pragma unroll
            for (int r = 0; r < 4; r++) {
                sc[i][r] = __builtin_amdgcn_exp2f(sc[i][r] - m_i);
                rs += sc[i][r];
            }
        l_i += rs;

#pragma unroll
        for (int i = 0; i < 4; i++) {
            uint2 t;
            t.x = pack2(sc[i][0], sc[i][1]);
            t.y = pack2(sc[i][2], sc[i][3]);
            *(uint2*)&Pst[cidx * 36 + 8 * i + 2 * quad] = t;
        }
        bf16x8 bP0 = *(const bf16x8*)&Pst[cidx * 36 + 4 * quad];
        bf16x8 bP1 = *(const bf16x8*)&Pst[cidx * 36 + 16 + 4 * quad];

#pragma unroll
        for (int i = 0; i < 4; i++) {
            bf16x8 aV0 = *(const bf16x8*)&Vs[(i * 16 + cidx) * 64 + pb0];
            bf16x8 aV1 = *(const bf16x8*)&Vs[(i * 16 + cidx) * 64 + pb1];
            __builtin_amdgcn_s_setprio(1);
            Oc[i] = __builtin_amdgcn_mfma_f32_16x16x32_bf16(aV0, bP0, Oc[i], 0, 0, 0);
            Oc[i] = __builtin_amdgcn_mfma_f32_16x16x32_bf16(aV1, bP1, Oc[i], 0, 0, 0);
            __builtin_amdgcn_s_setprio(0);
        }
    }

    float lr = l_i;
    lr += __shfl_xor(lr, 16);
    lr += __shfl_xor(lr, 32);
    float inv = 1.f / lr;
#pragma unroll
    for (int i = 0; i < 4; i++) {
        uint2 t;
        t.x = pack2(Oc[i][0] * inv, Oc[i][1] * inv);
        t.y = pack2(Oc[i][2] * inv, Oc[i][3] * inv);
        *(uint2*)&Pst[cidx * 36 + 8 * i + 2 * quad] = t;
    }
    int r2 = lane >> 2, g2 = (lane & 3) * 8;
    uint4 o0v = *(const uint4*)&Pst[r2 * 36 + g2];
    uint4 o1v = *(const uint4*)&Pst[r2 * 36 + g2 + 4];
    bf16* orow = o + (size_t)(m0 + w * 16 + r2) * 1024 + h * 64;
    *(uint4*)(orow + g2 * 2) = o0v;
    *(uint4*)(orow + g2 * 2 + 8) = o1v;
}

// ---------------------------------------------------------------------------
extern "C" void kernel_launch(void* const* d_in, const int* in_sizes, int n_in,
                              void* d_out, int out_size, void* d_ws, size_t ws_size,
                              hipStream_t stream)
{
    const int S = 2048;

    const float* x    = (const float*)d_in[0];
    const float* ln1g = (const float*)d_in[1];
    const float* ln1b = (const float*)d_in[2];
    const float* Wq   = (const float*)d_in[3];
    const float* Wk   = (const float*)d_in[4];
    const float* Wv   = (const float*)d_in[5];
    const float* Wo   = (const float*)d_in[6];
    const float* ln2g = (const float*)d_in[7];
    const float* ln2b = (const float*)d_in[8];
    const float* W1   = (const float*)d_in[9];
    const float* W2   = (const float*)d_in[10];
    const float* W3   = (const float*)d_in[11];
    float* out = (float*)d_out;

    const size_t M2 = 1u << 21;        // 2M bf16 elems (one 4MB slot)
    bf16* r0 = (bf16*)d_ws;
    bf16* r1 = r0 + M2;
    bf16* r2 = r1 + M2;
    bf16* r3 = r2 + M2;
    bf16* pb0 = (bf16*)out;
    bf16* pb1 = pb0 + 2 * M2;
    float* out0 = out;
    float* out1 = out + (1u << 21);

    // 1. LN1 both -> r0,r1; WqT/WkT/WvT -> pb0[0:3M elems)
    prep1_kernel<<<7168, 256, 0, stream>>>(x, ln1g, ln1b, r0, r1,
                                           Wq, Wk, Wv, pb0);

    // 2. mode6F: vt0 -> P1a(pb1), vt1 -> P1b  (WvT at pb0+M2)
    mfma_gemm<6><<<dim3(16, 32, 2), 256, 0, stream>>>(
        r0, pb0 + M2, pb1, nullptr, r1, pb1 + M2, S, 1024, 1024);

    // 3. QK(b0): q0 -> r2, k0 -> r3 (RoPE)
    mfma_gemm<1><<<dim3(16, 32, 2), 256, 0, stream>>>(
        r0, pb0, r2, nullptr, nullptr, r3, S, 1024, 1024);

    // 4. QK(b1): q1 -> r0 (h0 dead), k1 -> pb0+M2 (WvT dead)
    mfma_gemm<1><<<dim3(16, 32, 2), 256, 0, stream>>>(
        r1, pb0, r0, nullptr, nullptr, pb0 + M2, S, 1024, 1024);

    // 5. attnF: ao0 -> r1 (h1 dead), ao1 -> pb0 (WqT/WkT dead)
    attn_kernel<<<dim3(64, 16, 2), 128, 0, stream>>>(
        r2, r3, pb1, r1, r0, pb0 + M2, pb1 + M2, pb0);

    // 6a. WoT -> r2 (q0 dead)
    tconv_wo_kernel<<<dim3(2, 32, 16), 256, 0, stream>>>(Wo, r2);

    // 6b. mode2F: x2_0 = x0 + ao0@Wo -> r3 (k0 dead); x2_1 -> r0 (q1 dead)
    mfma_gemm<2><<<dim3(16, 32, 2), 256, 0, stream>>>(
        r1, r2, r3, x, pb0, r0, S, 1024, 1024);

    // 7a. prep2(b0)+W3T: h2_0 -> P1a (vt0 dead); W12T -> pb0 (ao1/k1 dead);
    //     W3T -> P1b (vt1 dead)
    prep2_kernel<<<8192, 256, 0, stream>>>(r3, ln2g, ln2b, pb1, W1, W2, pb0,
                                           W3, pb1 + M2);

    // 7b. swiglu(b0): sb0 -> r1..r2 (ao0, WoT dead)
    swiglu_gemm<<<dim3(32, 16), 256, 0, stream>>>(pb1, pb0, pb0 + M2, r1);

    // 7d. out0 = x2_0 + sb0@W3 -> pb0 fp32 (W12T dead)
    mfma_gemm<4><<<dim3(16, 32, 1), 256, 0, stream>>>(
        r1, pb1 + M2, out0, r3, nullptr, nullptr, S, 1024, 2048);

    // 8a. prep2(b1): x2_1=r0 -> h2_1 -> r3 (x2_0 dead); W12T -> pb1
    prep2_kernel<<<6144, 256, 0, stream>>>(r0, ln2g, ln2b, r3, W1, W2, pb1,
                                           nullptr, nullptr);

    // 8b. swiglu(b1): sb1 -> r1..r2 (sb0 dead)
    swiglu_gemm<<<dim3(32, 16), 256, 0, stream>>>(r3, pb1, pb1 + M2, r1);

    // 8c. W3T -> r3 (h2_1 dead)
    tconv_kernel<<<dim3(32, 64), 256, 0, stream>>>(W3, r3, 2048, 1024);

    // 8d. out1 = x2_1 + sb1@W3 -> pb1 fp32 (W12T dead)
    mfma_gemm<4><<<dim3(16, 32, 1), 256, 0, stream>>>(
        r1, r3, out1, r0, nullptr, nullptr, S, 1024, 2048);
}